// Round 8
// baseline (754.271 us; speedup 1.0000x reference)
//
#include <hip/hip_runtime.h>
#include <stdint.h>

typedef __attribute__((ext_vector_type(8))) short short8;
typedef __attribute__((ext_vector_type(4))) float floatx4;

__device__ __forceinline__ float bf2f(uint16_t u) {
  union { uint32_t u; float f; } c; c.u = (uint32_t)u << 16; return c.f;
}
__device__ __forceinline__ uint16_t f2bf(float f) {
  union { float f; uint32_t u; } c; c.f = f;
  return (uint16_t)((c.u + 0x7fffu + ((c.u >> 16) & 1u)) >> 16);
}

// ---------------- convert f32 -> bf16, 8 elems/thread ----------------
__global__ void k_cvt_bf16(const float* __restrict__ in, uint16_t* __restrict__ out, int n8) {
  int i = blockIdx.x * blockDim.x + threadIdx.x;
  if (i >= n8) return;
  const floatx4* p = (const floatx4*)in + (size_t)i * 2;
  floatx4 a = p[0], b = p[1];
  short8 o;
  o[0] = (short)f2bf(a[0]); o[1] = (short)f2bf(a[1]);
  o[2] = (short)f2bf(a[2]); o[3] = (short)f2bf(a[3]);
  o[4] = (short)f2bf(b[0]); o[5] = (short)f2bf(b[1]);
  o[6] = (short)f2bf(b[2]); o[7] = (short)f2bf(b[3]);
  *((short8*)out + i) = o;
}

// ---- GEMM mainloop: C(128x128) = A[(arow0+m0..)xK] * Wt(NxK)^T, bf16 in ----
// 256 threads = 4 waves (2x2), each wave 64x64 out = 4x4 frags of 16x16x32.
__device__ __forceinline__ void gemm_main(
    const uint16_t* __restrict__ A, const uint16_t* __restrict__ Wt, int K,
    int arow0, uint16_t* lds_a, uint16_t* lds_b, int m0, int n0, floatx4 acc[4][4]) {
  const int t = threadIdx.x;
  const int wave = t >> 6, lane = t & 63;
  const int wr = wave >> 1, wc = wave & 1;
  const int r = t >> 2;            // staging row 0..63
  const int ce = (t & 3) * 8;      // element offset within 32-wide k tile
  short8* wA0 = (short8*)((char*)lds_a + (size_t)t * 16);
  short8* wA1 = (short8*)((char*)lds_a + (size_t)t * 16 + 4096);
  short8* wB0 = (short8*)((char*)lds_b + (size_t)t * 16);
  short8* wB1 = (short8*)((char*)lds_b + (size_t)t * 16 + 4096);
  const int ksub = lane >> 4, rrow = lane & 15;
  const size_t offA0 = (size_t)(arow0 + m0 + r) * K + ce;
  const size_t offA1 = offA0 + (size_t)64 * K;
  const size_t offB0 = (size_t)(n0 + r) * K + ce;
  const size_t offB1 = offB0 + (size_t)64 * K;

  for (int k0 = 0; k0 < K; k0 += 32) {
    short8 ra0 = *(const short8*)(A + offA0 + k0);
    short8 ra1 = *(const short8*)(A + offA1 + k0);
    short8 rb0 = *(const short8*)(Wt + offB0 + k0);
    short8 rb1 = *(const short8*)(Wt + offB1 + k0);
    *wA0 = ra0; *wA1 = ra1; *wB0 = rb0; *wB1 = rb1;
    __syncthreads();
    short8 af[4], bfr[4];
    const short8* pa = (const short8*)lds_a;
    const short8* pb = (const short8*)lds_b;
#pragma unroll
    for (int i = 0; i < 4; i++)
      af[i] = pa[(wr * 64 + i * 16 + rrow) * 4 + ksub];
#pragma unroll
    for (int j = 0; j < 4; j++)
      bfr[j] = pb[(wc * 64 + j * 16 + rrow) * 4 + ksub];
#pragma unroll
    for (int i = 0; i < 4; i++)
#pragma unroll
      for (int j = 0; j < 4; j++)
        acc[i][j] = __builtin_amdgcn_mfma_f32_16x16x32_bf16(af[i], bfr[j], acc[i][j], 0, 0, 0);
    __syncthreads();
  }
}

// ---- GEMM 1: qkv_chunk = x_bf[rows] @ W_in^T + b_in  (bf16 out, N=3072) ----
__global__ __launch_bounds__(256, 2) void k_gemm_qkv(
    const uint16_t* __restrict__ A, const uint16_t* __restrict__ Wt,
    const float* __restrict__ bias, uint16_t* __restrict__ C,
    int arow0, int K, int N) {
  __shared__ __align__(16) uint16_t lds_a[128 * 32];
  __shared__ __align__(16) uint16_t lds_b[128 * 32];
  floatx4 acc[4][4];
#pragma unroll
  for (int i = 0; i < 4; i++)
#pragma unroll
    for (int j = 0; j < 4; j++) acc[i][j] = (floatx4){0.f, 0.f, 0.f, 0.f};
  const int m0 = blockIdx.x * 128, n0 = blockIdx.y * 128;
  gemm_main(A, Wt, K, arow0, lds_a, lds_b, m0, n0, acc);
  const int wave = threadIdx.x >> 6, lane = threadIdx.x & 63;
  const int wr = wave >> 1, wc = wave & 1;
  const int cq = lane >> 4, cr = lane & 15;   // C/D: col=lane&15, row=(lane>>4)*4+reg
#pragma unroll
  for (int j = 0; j < 4; j++) {
    int col = n0 + wc * 64 + j * 16 + cr;
    float bv = bias[col];
#pragma unroll
    for (int i = 0; i < 4; i++) {
      int row = m0 + wr * 64 + i * 16 + cq * 4;   // chunk-local
#pragma unroll
      for (int rg = 0; rg < 4; rg++)
        C[(size_t)(row + rg) * N + col] = f2bf(acc[i][j][rg] + bv);
    }
  }
}

// ---- GEMM 2: y = x + gate*(attn_bf @ W_out^T + b_out), f32 y (N=1024) ------
__global__ __launch_bounds__(256, 2) void k_gemm_out(
    const uint16_t* __restrict__ A, const uint16_t* __restrict__ Wt,
    const float* __restrict__ bias, const float* __restrict__ xres,
    const float* __restrict__ gate, float* __restrict__ Y,
    int xrow0, int K, int N) {
  __shared__ __align__(16) uint16_t lds_a[128 * 32];
  __shared__ __align__(16) uint16_t lds_b[128 * 32];
  floatx4 acc[4][4];
#pragma unroll
  for (int i = 0; i < 4; i++)
#pragma unroll
    for (int j = 0; j < 4; j++) acc[i][j] = (floatx4){0.f, 0.f, 0.f, 0.f};
  const int m0 = blockIdx.x * 128, n0 = blockIdx.y * 128;
  gemm_main(A, Wt, K, 0, lds_a, lds_b, m0, n0, acc);
  const float g = gate[0];
  const int wave = threadIdx.x >> 6, lane = threadIdx.x & 63;
  const int wr = wave >> 1, wc = wave & 1;
  const int cq = lane >> 4, cr = lane & 15;
#pragma unroll
  for (int j = 0; j < 4; j++) {
    int col = n0 + wc * 64 + j * 16 + cr;
    float bv = bias[col];
#pragma unroll
    for (int i = 0; i < 4; i++) {
      int row = m0 + wr * 64 + i * 16 + cq * 4;   // chunk-local
#pragma unroll
      for (int rg = 0; rg < 4; rg++) {
        float o = acc[i][j][rg] + bv;
        float xv = xres[(size_t)(xrow0 + row + rg) * N + col];
        Y[(size_t)(row + rg) * N + col] = xv + g * o;
      }
    }
  }
}

// ---- window attention: W=4, HD=64; one wave per (window,head); bf16 --------
__global__ __launch_bounds__(256) void k_attn(
    const uint16_t* __restrict__ qkv, uint16_t* __restrict__ aout) {
  const int wave = threadIdx.x >> 6, lane = threadIdx.x & 63;
  const int gh = blockIdx.x * 4 + wave;
  const int g = gh >> 4, h = gh & 15;
  const uint16_t* base = qkv + (size_t)(g * 4) * 3072 + h * 64 + lane;
  float q[4], k[4], v[4];
#pragma unroll
  for (int i = 0; i < 4; i++) {
    q[i] = bf2f(base[(size_t)i * 3072]);
    k[i] = bf2f(base[(size_t)i * 3072 + 1024]);
    v[i] = bf2f(base[(size_t)i * 3072 + 2048]);
  }
  float s[4][4];
#pragma unroll
  for (int qi = 0; qi < 4; qi++)
#pragma unroll
    for (int ki = 0; ki < 4; ki++) s[qi][ki] = q[qi] * k[ki];
#pragma unroll
  for (int off = 32; off; off >>= 1)
#pragma unroll
    for (int qi = 0; qi < 4; qi++)
#pragma unroll
      for (int ki = 0; ki < 4; ki++)
        s[qi][ki] += __shfl_xor(s[qi][ki], off, 64);

  uint16_t* obase = aout + (size_t)(g * 4) * 1024 + h * 64 + lane;
#pragma unroll
  for (int qi = 0; qi < 4; qi++) {
    float a0 = s[qi][0] * 0.125f, a1 = s[qi][1] * 0.125f;
    float a2 = s[qi][2] * 0.125f, a3 = s[qi][3] * 0.125f;
    float m = fmaxf(fmaxf(a0, a1), fmaxf(a2, a3));
    float e0 = expf(a0 - m), e1 = expf(a1 - m), e2 = expf(a2 - m), e3 = expf(a3 - m);
    float inv = 1.f / (e0 + e1 + e2 + e3);
    float o = (e0 * v[0] + e1 * v[1] + e2 * v[2] + e3 * v[3]) * inv;
    obase[(size_t)qi * 1024] = f2bf(o);
  }
}

// ---- LayerNorm over D=1024, one wave per row; f32 in -> f32 OUT ------------
__global__ __launch_bounds__(256) void k_ln(
    const float* __restrict__ y, const float* __restrict__ gamma,
    const float* __restrict__ beta, float* __restrict__ out) {
  const int wave = threadIdx.x >> 6, lane = threadIdx.x & 63;
  const size_t row = (size_t)blockIdx.x * 4 + wave;
  const float* py = y + row * 1024 + lane * 16;
  float f[16];
#pragma unroll
  for (int c = 0; c < 4; c++) {
    floatx4 v = *(const floatx4*)(py + c * 4);
#pragma unroll
    for (int e = 0; e < 4; e++) f[c * 4 + e] = v[e];
  }
  float sum = 0.f, sq = 0.f;
#pragma unroll
  for (int j = 0; j < 16; j++) { sum += f[j]; sq += f[j] * f[j]; }
#pragma unroll
  for (int off = 32; off; off >>= 1) {
    sum += __shfl_xor(sum, off, 64);
    sq  += __shfl_xor(sq,  off, 64);
  }
  const float mu = sum * (1.f / 1024.f);
  const float var = sq * (1.f / 1024.f) - mu * mu;
  const float inv = rsqrtf(var + 1e-5f);
  const int c0 = lane * 16;
  float* po = out + row * 1024 + lane * 16;
#pragma unroll
  for (int c = 0; c < 4; c++) {
    floatx4 o;
#pragma unroll
    for (int e = 0; e < 4; e++) {
      int j = c * 4 + e;
      o[e] = (f[j] - mu) * inv * gamma[c0 + j] + beta[c0 + j];
    }
    *(floatx4*)(po + c * 4) = o;
  }
}

extern "C" void kernel_launch(void* const* d_in, const int* in_sizes, int n_in,
                              void* d_out, int out_size, void* d_ws, size_t ws_size,
                              hipStream_t stream) {
  const float* x     = (const float*)d_in[0];
  const float* w_in  = (const float*)d_in[1];
  const float* b_in  = (const float*)d_in[2];
  const float* w_out = (const float*)d_in[3];
  const float* b_out = (const float*)d_in[4];
  const float* gamma = (const float*)d_in[5];
  const float* beta  = (const float*)d_in[6];
  const float* gate  = (const float*)d_in[7];
  float* out = (float*)d_out;   // f32 OUTPUT (reference returns float32)

  const int M = 32768;  // B*N = 4*8192
  // ws layout (136 MiB): w_in_bf 6M | w_out_bf 2M | x_bf 64M | qkv_bf 48M | attn_bf 16M
  char* ws = (char*)d_ws;
  uint16_t* w_in_bf  = (uint16_t*)ws;
  uint16_t* w_out_bf = (uint16_t*)(ws + 6291456);
  uint16_t* x_bf     = (uint16_t*)(ws + 8388608);
  uint16_t* qkv_bf   = (uint16_t*)(ws + 8388608 + 67108864);
  uint16_t* attn_bf  = (uint16_t*)(ws + 8388608 + 67108864 + 50331648);
  float*    y_f32    = (float*)qkv_bf;   // reuse: qkv dead after attn (32M <= 48M)

  k_cvt_bf16<<<16384, 256, 0, stream>>>(x, x_bf, M * 1024 / 8);
  k_cvt_bf16<<<1536, 256, 0, stream>>>(w_in, w_in_bf, 393216);
  k_cvt_bf16<<<512, 256, 0, stream>>>(w_out, w_out_bf, 131072);

  const int CH = 8192;  // rows per chunk; windows (W=4) never cross chunks
  for (int c = 0; c < 4; c++) {
    const int r0 = c * CH;
    k_gemm_qkv<<<dim3(CH / 128, 3072 / 128), 256, 0, stream>>>(
        x_bf, w_in_bf, b_in, qkv_bf, r0, 1024, 3072);
    k_attn<<<(CH / 4) * 16 / 4, 256, 0, stream>>>(qkv_bf, attn_bf);
    k_gemm_out<<<dim3(CH / 128, 1024 / 128), 256, 0, stream>>>(
        attn_bf, w_out_bf, b_out, x, gate, y_f32, r0, 1024, 1024);
    k_ln<<<CH / 4, 256, 0, stream>>>(y_f32, gamma, beta, out + (size_t)r0 * 1024);
  }
}

// Round 9
// 717.887 us; speedup vs baseline: 1.0507x; 1.0507x over previous
//
#include <hip/hip_runtime.h>
#include <stdint.h>

typedef __attribute__((ext_vector_type(8))) short short8;
typedef __attribute__((ext_vector_type(4))) float floatx4;

__device__ __forceinline__ float bf2f(uint16_t u) {
  union { uint32_t u; float f; } c; c.u = (uint32_t)u << 16; return c.f;
}
__device__ __forceinline__ uint16_t f2bf(float f) {
  union { float f; uint32_t u; } c; c.f = f;
  return (uint16_t)((c.u + 0x7fffu + ((c.u >> 16) & 1u)) >> 16);
}
__device__ __forceinline__ void gload_lds16(const void* g, void* l) {
  __builtin_amdgcn_global_load_lds(
      (const __attribute__((address_space(1))) uint32_t*)g,
      (__attribute__((address_space(3))) uint32_t*)l, 16, 0, 0);
}

// ---------------- convert f32 -> bf16, 8 elems/thread ----------------
__global__ void k_cvt_bf16(const float* __restrict__ in, uint16_t* __restrict__ out, int n8) {
  int i = blockIdx.x * blockDim.x + threadIdx.x;
  if (i >= n8) return;
  const floatx4* p = (const floatx4*)in + (size_t)i * 2;
  floatx4 a = p[0], b = p[1];
  short8 o;
  o[0] = (short)f2bf(a[0]); o[1] = (short)f2bf(a[1]);
  o[2] = (short)f2bf(a[2]); o[3] = (short)f2bf(a[3]);
  o[4] = (short)f2bf(b[0]); o[5] = (short)f2bf(b[1]);
  o[6] = (short)f2bf(b[2]); o[7] = (short)f2bf(b[3]);
  *((short8*)out + i) = o;
}

// ---- GEMM mainloop: C(128x128) = A[(arow0+m0..)xK] * Wt(NxK)^T, bf16 in ----
// 256 threads = 4 waves (2x2), each wave 64x64 out = 4x4 frags of 16x16x32.
// Staging: global_load_lds width=16, wave-uniform LDS base + lane*16 (m97).
__device__ __forceinline__ void gemm_main(
    const uint16_t* __restrict__ A, const uint16_t* __restrict__ Wt, int K,
    int arow0, uint16_t* lds_a, uint16_t* lds_b, int m0, int n0, floatx4 acc[4][4]) {
  const int t = threadIdx.x;
  const int wave = t >> 6, lane = t & 63;
  const int wr = wave >> 1, wc = wave & 1;
  const int r = t >> 2;            // staging row 0..63
  const int cb = (t & 3) * 16;     // byte offset within 64B k-row
  const char* gA = (const char*)(A + (size_t)(arow0 + m0 + r) * K) + cb;
  const char* gB = (const char*)(Wt + (size_t)(n0 + r) * K) + cb;
  char* lA = (char*)lds_a + wave * 1024;   // wave-uniform base; HW adds lane*16
  char* lB = (char*)lds_b + wave * 1024;
  const size_t rowskip = (size_t)64 * K * 2;   // bytes: 64 rows down
  const int ksub = lane >> 4, rrow = lane & 15;

  for (int k0 = 0; k0 < K; k0 += 32) {
    gload_lds16(gA, lA);
    gload_lds16(gA + rowskip, lA + 4096);
    gload_lds16(gB, lB);
    gload_lds16(gB + rowskip, lB + 4096);
    gA += 64; gB += 64;            // advance 32 bf16
    __syncthreads();               // drains vmcnt before barrier
    short8 af[4], bfr[4];
    const short8* pa = (const short8*)lds_a;
    const short8* pb = (const short8*)lds_b;
#pragma unroll
    for (int i = 0; i < 4; i++)
      af[i] = pa[(wr * 64 + i * 16 + rrow) * 4 + ksub];
#pragma unroll
    for (int j = 0; j < 4; j++)
      bfr[j] = pb[(wc * 64 + j * 16 + rrow) * 4 + ksub];
#pragma unroll
    for (int i = 0; i < 4; i++)
#pragma unroll
      for (int j = 0; j < 4; j++)
        acc[i][j] = __builtin_amdgcn_mfma_f32_16x16x32_bf16(af[i], bfr[j], acc[i][j], 0, 0, 0);
    __syncthreads();
  }
}

// ---- GEMM 1: qkv_chunk = x_bf[rows] @ W_in^T + b_in  (bf16 out, N=3072) ----
__global__ __launch_bounds__(256, 2) void k_gemm_qkv(
    const uint16_t* __restrict__ A, const uint16_t* __restrict__ Wt,
    const float* __restrict__ bias, uint16_t* __restrict__ C,
    int arow0, int K, int N) {
  __shared__ __align__(16) uint16_t lds_a[128 * 32];
  __shared__ __align__(16) uint16_t lds_b[128 * 32];
  floatx4 acc[4][4];
#pragma unroll
  for (int i = 0; i < 4; i++)
#pragma unroll
    for (int j = 0; j < 4; j++) acc[i][j] = (floatx4){0.f, 0.f, 0.f, 0.f};
  const int m0 = blockIdx.x * 128, n0 = blockIdx.y * 128;
  gemm_main(A, Wt, K, arow0, lds_a, lds_b, m0, n0, acc);
  const int wave = threadIdx.x >> 6, lane = threadIdx.x & 63;
  const int wr = wave >> 1, wc = wave & 1;
  const int cq = lane >> 4, cr = lane & 15;   // C/D: col=lane&15, row=(lane>>4)*4+reg
#pragma unroll
  for (int j = 0; j < 4; j++) {
    int col = n0 + wc * 64 + j * 16 + cr;
    float bv = bias[col];
#pragma unroll
    for (int i = 0; i < 4; i++) {
      int row = m0 + wr * 64 + i * 16 + cq * 4;   // chunk-local
#pragma unroll
      for (int rg = 0; rg < 4; rg++)
        C[(size_t)(row + rg) * N + col] = f2bf(acc[i][j][rg] + bv);
    }
  }
}

// ---- GEMM 2: y = x + gate*(attn_bf @ W_out^T + b_out), f32 y (N=1024) ------
__global__ __launch_bounds__(256, 2) void k_gemm_out(
    const uint16_t* __restrict__ A, const uint16_t* __restrict__ Wt,
    const float* __restrict__ bias, const float* __restrict__ xres,
    const float* __restrict__ gate, float* __restrict__ Y,
    int xrow0, int K, int N) {
  __shared__ __align__(16) uint16_t lds_a[128 * 32];
  __shared__ __align__(16) uint16_t lds_b[128 * 32];
  floatx4 acc[4][4];
#pragma unroll
  for (int i = 0; i < 4; i++)
#pragma unroll
    for (int j = 0; j < 4; j++) acc[i][j] = (floatx4){0.f, 0.f, 0.f, 0.f};
  const int m0 = blockIdx.x * 128, n0 = blockIdx.y * 128;
  gemm_main(A, Wt, K, 0, lds_a, lds_b, m0, n0, acc);
  const float g = gate[0];
  const int wave = threadIdx.x >> 6, lane = threadIdx.x & 63;
  const int wr = wave >> 1, wc = wave & 1;
  const int cq = lane >> 4, cr = lane & 15;
#pragma unroll
  for (int j = 0; j < 4; j++) {
    int col = n0 + wc * 64 + j * 16 + cr;
    float bv = bias[col];
#pragma unroll
    for (int i = 0; i < 4; i++) {
      int row = m0 + wr * 64 + i * 16 + cq * 4;   // chunk-local
#pragma unroll
      for (int rg = 0; rg < 4; rg++) {
        float o = acc[i][j][rg] + bv;
        float xv = xres[(size_t)(xrow0 + row + rg) * N + col];
        Y[(size_t)(row + rg) * N + col] = xv + g * o;
      }
    }
  }
}

// ---- window attention: W=4, HD=64; one wave per (window,head); bf16 --------
__global__ __launch_bounds__(256) void k_attn(
    const uint16_t* __restrict__ qkv, uint16_t* __restrict__ aout) {
  const int wave = threadIdx.x >> 6, lane = threadIdx.x & 63;
  const int gh = blockIdx.x * 4 + wave;
  const int g = gh >> 4, h = gh & 15;
  const uint16_t* base = qkv + (size_t)(g * 4) * 3072 + h * 64 + lane;
  float q[4], k[4], v[4];
#pragma unroll
  for (int i = 0; i < 4; i++) {
    q[i] = bf2f(base[(size_t)i * 3072]);
    k[i] = bf2f(base[(size_t)i * 3072 + 1024]);
    v[i] = bf2f(base[(size_t)i * 3072 + 2048]);
  }
  float s[4][4];
#pragma unroll
  for (int qi = 0; qi < 4; qi++)
#pragma unroll
    for (int ki = 0; ki < 4; ki++) s[qi][ki] = q[qi] * k[ki];
#pragma unroll
  for (int off = 32; off; off >>= 1)
#pragma unroll
    for (int qi = 0; qi < 4; qi++)
#pragma unroll
      for (int ki = 0; ki < 4; ki++)
        s[qi][ki] += __shfl_xor(s[qi][ki], off, 64);

  uint16_t* obase = aout + (size_t)(g * 4) * 1024 + h * 64 + lane;
#pragma unroll
  for (int qi = 0; qi < 4; qi++) {
    float a0 = s[qi][0] * 0.125f, a1 = s[qi][1] * 0.125f;
    float a2 = s[qi][2] * 0.125f, a3 = s[qi][3] * 0.125f;
    float m = fmaxf(fmaxf(a0, a1), fmaxf(a2, a3));
    float e0 = expf(a0 - m), e1 = expf(a1 - m), e2 = expf(a2 - m), e3 = expf(a3 - m);
    float inv = 1.f / (e0 + e1 + e2 + e3);
    float o = (e0 * v[0] + e1 * v[1] + e2 * v[2] + e3 * v[3]) * inv;
    obase[(size_t)qi * 1024] = f2bf(o);
  }
}

// ---- LayerNorm over D=1024, one wave per row; f32 in -> f32 OUT ------------
__global__ __launch_bounds__(256) void k_ln(
    const float* __restrict__ y, const float* __restrict__ gamma,
    const float* __restrict__ beta, float* __restrict__ out) {
  const int wave = threadIdx.x >> 6, lane = threadIdx.x & 63;
  const size_t row = (size_t)blockIdx.x * 4 + wave;
  const float* py = y + row * 1024 + lane * 16;
  float f[16];
#pragma unroll
  for (int c = 0; c < 4; c++) {
    floatx4 v = *(const floatx4*)(py + c * 4);
#pragma unroll
    for (int e = 0; e < 4; e++) f[c * 4 + e] = v[e];
  }
  float sum = 0.f, sq = 0.f;
#pragma unroll
  for (int j = 0; j < 16; j++) { sum += f[j]; sq += f[j] * f[j]; }
#pragma unroll
  for (int off = 32; off; off >>= 1) {
    sum += __shfl_xor(sum, off, 64);
    sq  += __shfl_xor(sq,  off, 64);
  }
  const float mu = sum * (1.f / 1024.f);
  const float var = sq * (1.f / 1024.f) - mu * mu;
  const float inv = rsqrtf(var + 1e-5f);
  const int c0 = lane * 16;
  float* po = out + row * 1024 + lane * 16;
#pragma unroll
  for (int c = 0; c < 4; c++) {
    floatx4 o;
#pragma unroll
    for (int e = 0; e < 4; e++) {
      int j = c * 4 + e;
      o[e] = (f[j] - mu) * inv * gamma[c0 + j] + beta[c0 + j];
    }
    *(floatx4*)(po + c * 4) = o;
  }
}

extern "C" void kernel_launch(void* const* d_in, const int* in_sizes, int n_in,
                              void* d_out, int out_size, void* d_ws, size_t ws_size,
                              hipStream_t stream) {
  const float* x     = (const float*)d_in[0];
  const float* w_in  = (const float*)d_in[1];
  const float* b_in  = (const float*)d_in[2];
  const float* w_out = (const float*)d_in[3];
  const float* b_out = (const float*)d_in[4];
  const float* gamma = (const float*)d_in[5];
  const float* beta  = (const float*)d_in[6];
  const float* gate  = (const float*)d_in[7];
  float* out = (float*)d_out;   // f32 OUTPUT (reference returns float32)

  const int M = 32768;  // B*N = 4*8192
  // ws layout (136 MiB): w_in_bf 6M | w_out_bf 2M | x_bf 64M | qkv_bf 48M | attn_bf 16M
  char* ws = (char*)d_ws;
  uint16_t* w_in_bf  = (uint16_t*)ws;
  uint16_t* w_out_bf = (uint16_t*)(ws + 6291456);
  uint16_t* x_bf     = (uint16_t*)(ws + 8388608);
  uint16_t* qkv_bf   = (uint16_t*)(ws + 8388608 + 67108864);
  uint16_t* attn_bf  = (uint16_t*)(ws + 8388608 + 67108864 + 50331648);
  float*    y_f32    = (float*)qkv_bf;   // reuse: qkv dead after attn (32M <= 48M)

  k_cvt_bf16<<<16384, 256, 0, stream>>>(x, x_bf, M * 1024 / 8);
  k_cvt_bf16<<<1536, 256, 0, stream>>>(w_in, w_in_bf, 393216);
  k_cvt_bf16<<<512, 256, 0, stream>>>(w_out, w_out_bf, 131072);

  const int CH = 8192;  // rows per chunk; windows (W=4) never cross chunks
  for (int c = 0; c < 4; c++) {
    const int r0 = c * CH;
    k_gemm_qkv<<<dim3(CH / 128, 3072 / 128), 256, 0, stream>>>(
        x_bf, w_in_bf, b_in, qkv_bf, r0, 1024, 3072);
    k_attn<<<(CH / 4) * 16 / 4, 256, 0, stream>>>(qkv_bf, attn_bf);
    k_gemm_out<<<dim3(CH / 128, 1024 / 128), 256, 0, stream>>>(
        attn_bf, w_out_bf, b_out, x, gate, y_f32, r0, 1024, 1024);
    k_ln<<<CH / 4, 256, 0, stream>>>(y_f32, gamma, beta, out + (size_t)r0 * 1024);
  }
}

// Round 10
// 688.999 us; speedup vs baseline: 1.0947x; 1.0419x over previous
//
#include <hip/hip_runtime.h>
#include <stdint.h>

typedef __attribute__((ext_vector_type(8))) short short8;
typedef __attribute__((ext_vector_type(4))) float floatx4;

__device__ __forceinline__ float bf2f(uint16_t u) {
  union { uint32_t u; float f; } c; c.u = (uint32_t)u << 16; return c.f;
}
__device__ __forceinline__ uint16_t f2bf(float f) {
  union { float f; uint32_t u; } c; c.f = f;
  return (uint16_t)((c.u + 0x7fffu + ((c.u >> 16) & 1u)) >> 16);
}
__device__ __forceinline__ void gload_lds16(const void* g, void* l) {
  __builtin_amdgcn_global_load_lds(
      (const __attribute__((address_space(1))) uint32_t*)g,
      (__attribute__((address_space(3))) uint32_t*)l, 16, 0, 0);
}

// ---------------- convert f32 -> bf16, 8 elems/thread ----------------
__global__ void k_cvt_bf16(const float* __restrict__ in, uint16_t* __restrict__ out, int n8) {
  int i = blockIdx.x * blockDim.x + threadIdx.x;
  if (i >= n8) return;
  const floatx4* p = (const floatx4*)in + (size_t)i * 2;
  floatx4 a = p[0], b = p[1];
  short8 o;
  o[0] = (short)f2bf(a[0]); o[1] = (short)f2bf(a[1]);
  o[2] = (short)f2bf(a[2]); o[3] = (short)f2bf(a[3]);
  o[4] = (short)f2bf(b[0]); o[5] = (short)f2bf(b[1]);
  o[6] = (short)f2bf(b[2]); o[7] = (short)f2bf(b[3]);
  *((short8*)out + i) = o;
}

// ---- GEMM mainloop: C(128x128) = A[(arow0+m0..)xK] * Wt(NxK)^T, bf16 in ----
// 256 threads = 4 waves (2x2), each wave 64x64 out = 4x4 frags of 16x16x32.
// Staging: global_load_lds width=16, wave-uniform LDS base + lane*16 (m97).
__device__ __forceinline__ void gemm_main(
    const uint16_t* __restrict__ A, const uint16_t* __restrict__ Wt, int K,
    int arow0, uint16_t* lds_a, uint16_t* lds_b, int m0, int n0, floatx4 acc[4][4]) {
  const int t = threadIdx.x;
  const int wave = t >> 6, lane = t & 63;
  const int wr = wave >> 1, wc = wave & 1;
  const int r = t >> 2;            // staging row 0..63
  const int cb = (t & 3) * 16;     // byte offset within 64B k-row
  const char* gA = (const char*)(A + (size_t)(arow0 + m0 + r) * K) + cb;
  const char* gB = (const char*)(Wt + (size_t)(n0 + r) * K) + cb;
  char* lA = (char*)lds_a + wave * 1024;   // wave-uniform base; HW adds lane*16
  char* lB = (char*)lds_b + wave * 1024;
  const size_t rowskip = (size_t)64 * K * 2;   // bytes: 64 rows down
  const int ksub = lane >> 4, rrow = lane & 15;

  for (int k0 = 0; k0 < K; k0 += 32) {
    gload_lds16(gA, lA);
    gload_lds16(gA + rowskip, lA + 4096);
    gload_lds16(gB, lB);
    gload_lds16(gB + rowskip, lB + 4096);
    gA += 64; gB += 64;            // advance 32 bf16
    __syncthreads();               // drains vmcnt before barrier
    short8 af[4], bfr[4];
    const short8* pa = (const short8*)lds_a;
    const short8* pb = (const short8*)lds_b;
#pragma unroll
    for (int i = 0; i < 4; i++)
      af[i] = pa[(wr * 64 + i * 16 + rrow) * 4 + ksub];
#pragma unroll
    for (int j = 0; j < 4; j++)
      bfr[j] = pb[(wc * 64 + j * 16 + rrow) * 4 + ksub];
#pragma unroll
    for (int i = 0; i < 4; i++)
#pragma unroll
      for (int j = 0; j < 4; j++)
        acc[i][j] = __builtin_amdgcn_mfma_f32_16x16x32_bf16(af[i], bfr[j], acc[i][j], 0, 0, 0);
    __syncthreads();
  }
}

// ---- GEMM 1: qkv = x_bf[rows] @ W_in^T + b_in  (bf16 out, N=3072) ----------
__global__ __launch_bounds__(256, 2) void k_gemm_qkv(
    const uint16_t* __restrict__ A, const uint16_t* __restrict__ Wt,
    const float* __restrict__ bias, uint16_t* __restrict__ C,
    int arow0, int K, int N) {
  __shared__ __align__(16) uint16_t lds_a[128 * 32];
  __shared__ __align__(16) uint16_t lds_b[128 * 32];
  floatx4 acc[4][4];
#pragma unroll
  for (int i = 0; i < 4; i++)
#pragma unroll
    for (int j = 0; j < 4; j++) acc[i][j] = (floatx4){0.f, 0.f, 0.f, 0.f};
  const int m0 = blockIdx.x * 128, n0 = blockIdx.y * 128;
  gemm_main(A, Wt, K, arow0, lds_a, lds_b, m0, n0, acc);
  const int wave = threadIdx.x >> 6, lane = threadIdx.x & 63;
  const int wr = wave >> 1, wc = wave & 1;
  const int cq = lane >> 4, cr = lane & 15;   // C/D: col=lane&15, row=(lane>>4)*4+reg
#pragma unroll
  for (int j = 0; j < 4; j++) {
    int col = n0 + wc * 64 + j * 16 + cr;
    float bv = bias[col];
#pragma unroll
    for (int i = 0; i < 4; i++) {
      int row = m0 + wr * 64 + i * 16 + cq * 4;
#pragma unroll
      for (int rg = 0; rg < 4; rg++)
        C[(size_t)(row + rg) * N + col] = f2bf(acc[i][j][rg] + bv);
    }
  }
}

// ---- GEMM 2: y = x + gate*(attn_bf @ W_out^T + b_out), f32 y (N=1024) ------
__global__ __launch_bounds__(256, 2) void k_gemm_out(
    const uint16_t* __restrict__ A, const uint16_t* __restrict__ Wt,
    const float* __restrict__ bias, const float* __restrict__ xres,
    const float* __restrict__ gate, float* __restrict__ Y,
    int xrow0, int K, int N) {
  __shared__ __align__(16) uint16_t lds_a[128 * 32];
  __shared__ __align__(16) uint16_t lds_b[128 * 32];
  floatx4 acc[4][4];
#pragma unroll
  for (int i = 0; i < 4; i++)
#pragma unroll
    for (int j = 0; j < 4; j++) acc[i][j] = (floatx4){0.f, 0.f, 0.f, 0.f};
  const int m0 = blockIdx.x * 128, n0 = blockIdx.y * 128;
  gemm_main(A, Wt, K, 0, lds_a, lds_b, m0, n0, acc);
  const float g = gate[0];
  const int wave = threadIdx.x >> 6, lane = threadIdx.x & 63;
  const int wr = wave >> 1, wc = wave & 1;
  const int cq = lane >> 4, cr = lane & 15;
#pragma unroll
  for (int j = 0; j < 4; j++) {
    int col = n0 + wc * 64 + j * 16 + cr;
    float bv = bias[col];
#pragma unroll
    for (int i = 0; i < 4; i++) {
      int row = m0 + wr * 64 + i * 16 + cq * 4;
#pragma unroll
      for (int rg = 0; rg < 4; rg++) {
        float o = acc[i][j][rg] + bv;
        float xv = xres[(size_t)(xrow0 + row + rg) * N + col];
        Y[(size_t)(row + rg) * N + col] = xv + g * o;
      }
    }
  }
}

// ---- window attention: W=4, HD=64; one wave per (window,head); bf16 --------
__global__ __launch_bounds__(256) void k_attn(
    const uint16_t* __restrict__ qkv, uint16_t* __restrict__ aout) {
  const int wave = threadIdx.x >> 6, lane = threadIdx.x & 63;
  const int gh = blockIdx.x * 4 + wave;
  const int g = gh >> 4, h = gh & 15;
  const uint16_t* base = qkv + (size_t)(g * 4) * 3072 + h * 64 + lane;
  float q[4], k[4], v[4];
#pragma unroll
  for (int i = 0; i < 4; i++) {
    q[i] = bf2f(base[(size_t)i * 3072]);
    k[i] = bf2f(base[(size_t)i * 3072 + 1024]);
    v[i] = bf2f(base[(size_t)i * 3072 + 2048]);
  }
  float s[4][4];
#pragma unroll
  for (int qi = 0; qi < 4; qi++)
#pragma unroll
    for (int ki = 0; ki < 4; ki++) s[qi][ki] = q[qi] * k[ki];
#pragma unroll
  for (int off = 32; off; off >>= 1)
#pragma unroll
    for (int qi = 0; qi < 4; qi++)
#pragma unroll
      for (int ki = 0; ki < 4; ki++)
        s[qi][ki] += __shfl_xor(s[qi][ki], off, 64);

  uint16_t* obase = aout + (size_t)(g * 4) * 1024 + h * 64 + lane;
#pragma unroll
  for (int qi = 0; qi < 4; qi++) {
    float a0 = s[qi][0] * 0.125f, a1 = s[qi][1] * 0.125f;
    float a2 = s[qi][2] * 0.125f, a3 = s[qi][3] * 0.125f;
    float m = fmaxf(fmaxf(a0, a1), fmaxf(a2, a3));
    float e0 = expf(a0 - m), e1 = expf(a1 - m), e2 = expf(a2 - m), e3 = expf(a3 - m);
    float inv = 1.f / (e0 + e1 + e2 + e3);
    float o = (e0 * v[0] + e1 * v[1] + e2 * v[2] + e3 * v[3]) * inv;
    obase[(size_t)qi * 1024] = f2bf(o);
  }
}

// ---- LayerNorm over D=1024, one wave per row; f32 in -> f32 OUT ------------
__global__ __launch_bounds__(256) void k_ln(
    const float* __restrict__ y, const float* __restrict__ gamma,
    const float* __restrict__ beta, float* __restrict__ out) {
  const int wave = threadIdx.x >> 6, lane = threadIdx.x & 63;
  const size_t row = (size_t)blockIdx.x * 4 + wave;
  const float* py = y + row * 1024 + lane * 16;
  float f[16];
#pragma unroll
  for (int c = 0; c < 4; c++) {
    floatx4 v = *(const floatx4*)(py + c * 4);
#pragma unroll
    for (int e = 0; e < 4; e++) f[c * 4 + e] = v[e];
  }
  float sum = 0.f, sq = 0.f;
#pragma unroll
  for (int j = 0; j < 16; j++) { sum += f[j]; sq += f[j] * f[j]; }
#pragma unroll
  for (int off = 32; off; off >>= 1) {
    sum += __shfl_xor(sum, off, 64);
    sq  += __shfl_xor(sq,  off, 64);
  }
  const float mu = sum * (1.f / 1024.f);
  const float var = sq * (1.f / 1024.f) - mu * mu;
  const float inv = rsqrtf(var + 1e-5f);
  const int c0 = lane * 16;
  float* po = out + row * 1024 + lane * 16;
#pragma unroll
  for (int c = 0; c < 4; c++) {
    floatx4 o;
#pragma unroll
    for (int e = 0; e < 4; e++) {
      int j = c * 4 + e;
      o[e] = (f[j] - mu) * inv * gamma[c0 + j] + beta[c0 + j];
    }
    *(floatx4*)(po + c * 4) = o;
  }
}

extern "C" void kernel_launch(void* const* d_in, const int* in_sizes, int n_in,
                              void* d_out, int out_size, void* d_ws, size_t ws_size,
                              hipStream_t stream) {
  const float* x     = (const float*)d_in[0];
  const float* w_in  = (const float*)d_in[1];
  const float* b_in  = (const float*)d_in[2];
  const float* w_out = (const float*)d_in[3];
  const float* b_out = (const float*)d_in[4];
  const float* gamma = (const float*)d_in[5];
  const float* beta  = (const float*)d_in[6];
  const float* gate  = (const float*)d_in[7];
  float* out = (float*)d_out;   // f32 OUTPUT

  const int M = 32768;  // B*N = 4*8192
  char* ws = (char*)d_ws;
  uint16_t* w_in_bf  = (uint16_t*)ws;                   // 6 MiB
  uint16_t* w_out_bf = (uint16_t*)(ws + 6291456);       // 2 MiB
  uint16_t* x_bf     = (uint16_t*)(ws + 8388608);       // 64 MiB

  k_cvt_bf16<<<16384, 256, 0, stream>>>(x, x_bf, M * 1024 / 8);
  k_cvt_bf16<<<1536, 256, 0, stream>>>(w_in, w_in_bf, 393216);
  k_cvt_bf16<<<512, 256, 0, stream>>>(w_out, w_out_bf, 131072);

  const size_t full_need = 8388608ull + 67108864ull + 201326592ull + 67108864ull; // 344 MiB
  if (ws_size >= full_need) {
    // full-M path: qkv 192 MiB | attn 64 MiB; y_f32 reuses qkv (128 <= 192)
    uint16_t* qkv_bf  = (uint16_t*)(ws + 8388608 + 67108864);
    uint16_t* attn_bf = (uint16_t*)(ws + 8388608 + 67108864 + 201326592);
    float*    y_f32   = (float*)qkv_bf;
    k_gemm_qkv<<<dim3(M / 128, 3072 / 128), 256, 0, stream>>>(
        x_bf, w_in_bf, b_in, qkv_bf, 0, 1024, 3072);
    k_attn<<<(M / 4) * 16 / 4, 256, 0, stream>>>(qkv_bf, attn_bf);
    k_gemm_out<<<dim3(M / 128, 1024 / 128), 256, 0, stream>>>(
        attn_bf, w_out_bf, b_out, x, gate, y_f32, 0, 1024, 1024);
    k_ln<<<M / 4, 256, 0, stream>>>(y_f32, gamma, beta, out);
  } else {
    // proven 4-chunk fallback
    uint16_t* qkv_bf  = (uint16_t*)(ws + 8388608 + 67108864);
    uint16_t* attn_bf = (uint16_t*)(ws + 8388608 + 67108864 + 50331648);
    float*    y_f32   = (float*)qkv_bf;
    const int CH = 8192;
    for (int c = 0; c < 4; c++) {
      const int r0 = c * CH;
      k_gemm_qkv<<<dim3(CH / 128, 3072 / 128), 256, 0, stream>>>(
          x_bf, w_in_bf, b_in, qkv_bf, r0, 1024, 3072);
      k_attn<<<(CH / 4) * 16 / 4, 256, 0, stream>>>(qkv_bf, attn_bf);
      k_gemm_out<<<dim3(CH / 128, 1024 / 128), 256, 0, stream>>>(
          attn_bf, w_out_bf, b_out, x, gate, y_f32, r0, 1024, 1024);
      k_ln<<<CH / 4, 256, 0, stream>>>(y_f32, gamma, beta, out + (size_t)r0 * 1024);
    }
  }
}

// Round 11
// 666.266 us; speedup vs baseline: 1.1321x; 1.0341x over previous
//
#include <hip/hip_runtime.h>
#include <stdint.h>

typedef __attribute__((ext_vector_type(8))) short short8;
typedef __attribute__((ext_vector_type(4))) float floatx4;

__device__ __forceinline__ float bf2f(uint16_t u) {
  union { uint32_t u; float f; } c; c.u = (uint32_t)u << 16; return c.f;
}
__device__ __forceinline__ uint16_t f2bf(float f) {
  union { float f; uint32_t u; } c; c.f = f;
  return (uint16_t)((c.u + 0x7fffu + ((c.u >> 16) & 1u)) >> 16);
}
__device__ __forceinline__ void gload_lds16(const void* g, void* l) {
  __builtin_amdgcn_global_load_lds(
      (const __attribute__((address_space(1))) uint32_t*)g,
      (__attribute__((address_space(3))) uint32_t*)l, 16, 0, 0);
}

// ---------------- convert f32 -> bf16, 8 elems/thread ----------------
__global__ void k_cvt_bf16(const float* __restrict__ in, uint16_t* __restrict__ out, int n8) {
  int i = blockIdx.x * blockDim.x + threadIdx.x;
  if (i >= n8) return;
  const floatx4* p = (const floatx4*)in + (size_t)i * 2;
  floatx4 a = p[0], b = p[1];
  short8 o;
  o[0] = (short)f2bf(a[0]); o[1] = (short)f2bf(a[1]);
  o[2] = (short)f2bf(a[2]); o[3] = (short)f2bf(a[3]);
  o[4] = (short)f2bf(b[0]); o[5] = (short)f2bf(b[1]);
  o[6] = (short)f2bf(b[2]); o[7] = (short)f2bf(b[3]);
  *((short8*)out + i) = o;
}

// bijective XCD-chunk swizzle (m204, r==0 case) + column-fastest decode
__device__ __forceinline__ void decode_bid(int bid, int nwg, int ncols,
                                           int* m0, int* n0) {
  const int q = nwg >> 3;                 // nwg % 8 == 0 guaranteed by caller
  const int wg = (bid & 7) * q + (bid >> 3);
  *n0 = (wg % ncols) * 128;
  *m0 = (wg / ncols) * 128;
}

// ---- GEMM mainloop (double-buffered, 2-phase): C(128x128) = A * Wt^T -------
// 256 threads = 4 waves (2x2), each wave 64x64 out = 4x4 frags of 16x16x32.
// Staging: global_load_lds w=16 into buf^1 BEFORE compute of buf (overlap);
// one barrier per K-step (implicit vmcnt0+lgkm0 drain after MFMA).
__device__ __forceinline__ void gemm_main(
    const uint16_t* __restrict__ A, const uint16_t* __restrict__ Wt, int K,
    int arow0, uint16_t* lds_a, uint16_t* lds_b,  // each 2*128*32 elems
    int m0, int n0, floatx4 acc[4][4]) {
  const int t = threadIdx.x;
  const int wave = t >> 6, lane = t & 63;
  const int wr = wave >> 1, wc = wave & 1;
  const int r = t >> 2;            // staging row 0..63
  const int cb = (t & 3) * 16;     // byte offset within 64B k-row
  const char* gA = (const char*)(A + (size_t)(arow0 + m0 + r) * K) + cb;
  const char* gB = (const char*)(Wt + (size_t)(n0 + r) * K) + cb;
  const size_t rowskip = (size_t)64 * K * 2;   // bytes: 64 rows down
  const int ksub = lane >> 4, rrow = lane & 15;
  const int nT = K / 32;

  // prologue: stage tile 0 into buffer 0
  {
    char* lA = (char*)lds_a + wave * 1024;
    char* lB = (char*)lds_b + wave * 1024;
    gload_lds16(gA, lA);
    gload_lds16(gA + rowskip, lA + 4096);
    gload_lds16(gB, lB);
    gload_lds16(gB + rowskip, lB + 4096);
    gA += 64; gB += 64;
  }
  __syncthreads();

  int c = 0;
  for (int tt = 0; tt < nT; ++tt) {
    if (tt + 1 < nT) {             // issue next-tile stage into buf^1 (overlaps MFMA)
      char* lA = (char*)lds_a + (c ^ 1) * 8192 + wave * 1024;
      char* lB = (char*)lds_b + (c ^ 1) * 8192 + wave * 1024;
      gload_lds16(gA, lA);
      gload_lds16(gA + rowskip, lA + 4096);
      gload_lds16(gB, lB);
      gload_lds16(gB + rowskip, lB + 4096);
      gA += 64; gB += 64;
    }
    const short8* pa = (const short8*)(lds_a + c * 4096);
    const short8* pb = (const short8*)(lds_b + c * 4096);
    short8 af[4], bfr[4];
#pragma unroll
    for (int i = 0; i < 4; i++)
      af[i] = pa[(wr * 64 + i * 16 + rrow) * 4 + ksub];
#pragma unroll
    for (int j = 0; j < 4; j++)
      bfr[j] = pb[(wc * 64 + j * 16 + rrow) * 4 + ksub];
#pragma unroll
    for (int i = 0; i < 4; i++)
#pragma unroll
      for (int j = 0; j < 4; j++)
        acc[i][j] = __builtin_amdgcn_mfma_f32_16x16x32_bf16(af[i], bfr[j], acc[i][j], 0, 0, 0);
    __syncthreads();               // drains next-tile stage + all lds reads
    c ^= 1;
  }
}

// ---- GEMM 1: qkv = x_bf[rows] @ W_in^T + b_in  (bf16 out, N=3072) ----------
__global__ __launch_bounds__(256, 2) void k_gemm_qkv(
    const uint16_t* __restrict__ A, const uint16_t* __restrict__ Wt,
    const float* __restrict__ bias, uint16_t* __restrict__ C,
    int arow0, int K, int N, int nwg, int ncols) {
  __shared__ __align__(16) uint16_t lds_a[2 * 128 * 32];
  __shared__ __align__(16) uint16_t lds_b[2 * 128 * 32];
  floatx4 acc[4][4];
#pragma unroll
  for (int i = 0; i < 4; i++)
#pragma unroll
    for (int j = 0; j < 4; j++) acc[i][j] = (floatx4){0.f, 0.f, 0.f, 0.f};
  int m0, n0;
  decode_bid(blockIdx.x, nwg, ncols, &m0, &n0);
  gemm_main(A, Wt, K, arow0, lds_a, lds_b, m0, n0, acc);
  const int wave = threadIdx.x >> 6, lane = threadIdx.x & 63;
  const int wr = wave >> 1, wc = wave & 1;
  const int cq = lane >> 4, cr = lane & 15;   // C/D: col=lane&15, row=(lane>>4)*4+reg
#pragma unroll
  for (int j = 0; j < 4; j++) {
    int col = n0 + wc * 64 + j * 16 + cr;
    float bv = bias[col];
#pragma unroll
    for (int i = 0; i < 4; i++) {
      int row = m0 + wr * 64 + i * 16 + cq * 4;
#pragma unroll
      for (int rg = 0; rg < 4; rg++)
        C[(size_t)(row + rg) * N + col] = f2bf(acc[i][j][rg] + bv);
    }
  }
}

// ---- GEMM 2: y = x + gate*(attn_bf @ W_out^T + b_out), f32 y (N=1024) ------
__global__ __launch_bounds__(256, 2) void k_gemm_out(
    const uint16_t* __restrict__ A, const uint16_t* __restrict__ Wt,
    const float* __restrict__ bias, const float* __restrict__ xres,
    const float* __restrict__ gate, float* __restrict__ Y,
    int xrow0, int K, int N, int nwg, int ncols) {
  __shared__ __align__(16) uint16_t lds_a[2 * 128 * 32];
  __shared__ __align__(16) uint16_t lds_b[2 * 128 * 32];
  floatx4 acc[4][4];
#pragma unroll
  for (int i = 0; i < 4; i++)
#pragma unroll
    for (int j = 0; j < 4; j++) acc[i][j] = (floatx4){0.f, 0.f, 0.f, 0.f};
  int m0, n0;
  decode_bid(blockIdx.x, nwg, ncols, &m0, &n0);
  gemm_main(A, Wt, K, 0, lds_a, lds_b, m0, n0, acc);
  const float g = gate[0];
  const int wave = threadIdx.x >> 6, lane = threadIdx.x & 63;
  const int wr = wave >> 1, wc = wave & 1;
  const int cq = lane >> 4, cr = lane & 15;
#pragma unroll
  for (int j = 0; j < 4; j++) {
    int col = n0 + wc * 64 + j * 16 + cr;
    float bv = bias[col];
#pragma unroll
    for (int i = 0; i < 4; i++) {
      int row = m0 + wr * 64 + i * 16 + cq * 4;
#pragma unroll
      for (int rg = 0; rg < 4; rg++) {
        float o = acc[i][j][rg] + bv;
        float xv = xres[(size_t)(xrow0 + row + rg) * N + col];
        Y[(size_t)(row + rg) * N + col] = xv + g * o;
      }
    }
  }
}

// ---- window attention: W=4, HD=64; one wave per (window,head); bf16 --------
__global__ __launch_bounds__(256) void k_attn(
    const uint16_t* __restrict__ qkv, uint16_t* __restrict__ aout) {
  const int wave = threadIdx.x >> 6, lane = threadIdx.x & 63;
  const int gh = blockIdx.x * 4 + wave;
  const int g = gh >> 4, h = gh & 15;
  const uint16_t* base = qkv + (size_t)(g * 4) * 3072 + h * 64 + lane;
  float q[4], k[4], v[4];
#pragma unroll
  for (int i = 0; i < 4; i++) {
    q[i] = bf2f(base[(size_t)i * 3072]);
    k[i] = bf2f(base[(size_t)i * 3072 + 1024]);
    v[i] = bf2f(base[(size_t)i * 3072 + 2048]);
  }
  float s[4][4];
#pragma unroll
  for (int qi = 0; qi < 4; qi++)
#pragma unroll
    for (int ki = 0; ki < 4; ki++) s[qi][ki] = q[qi] * k[ki];
#pragma unroll
  for (int off = 32; off; off >>= 1)
#pragma unroll
    for (int qi = 0; qi < 4; qi++)
#pragma unroll
      for (int ki = 0; ki < 4; ki++)
        s[qi][ki] += __shfl_xor(s[qi][ki], off, 64);

  uint16_t* obase = aout + (size_t)(g * 4) * 1024 + h * 64 + lane;
#pragma unroll
  for (int qi = 0; qi < 4; qi++) {
    float a0 = s[qi][0] * 0.125f, a1 = s[qi][1] * 0.125f;
    float a2 = s[qi][2] * 0.125f, a3 = s[qi][3] * 0.125f;
    float m = fmaxf(fmaxf(a0, a1), fmaxf(a2, a3));
    float e0 = expf(a0 - m), e1 = expf(a1 - m), e2 = expf(a2 - m), e3 = expf(a3 - m);
    float inv = 1.f / (e0 + e1 + e2 + e3);
    float o = (e0 * v[0] + e1 * v[1] + e2 * v[2] + e3 * v[3]) * inv;
    obase[(size_t)qi * 1024] = f2bf(o);
  }
}

// ---- LayerNorm over D=1024, one wave per row; f32 in -> f32 OUT ------------
__global__ __launch_bounds__(256) void k_ln(
    const float* __restrict__ y, const float* __restrict__ gamma,
    const float* __restrict__ beta, float* __restrict__ out) {
  const int wave = threadIdx.x >> 6, lane = threadIdx.x & 63;
  const size_t row = (size_t)blockIdx.x * 4 + wave;
  const float* py = y + row * 1024 + lane * 16;
  float f[16];
#pragma unroll
  for (int c = 0; c < 4; c++) {
    floatx4 v = *(const floatx4*)(py + c * 4);
#pragma unroll
    for (int e = 0; e < 4; e++) f[c * 4 + e] = v[e];
  }
  float sum = 0.f, sq = 0.f;
#pragma unroll
  for (int j = 0; j < 16; j++) { sum += f[j]; sq += f[j] * f[j]; }
#pragma unroll
  for (int off = 32; off; off >>= 1) {
    sum += __shfl_xor(sum, off, 64);
    sq  += __shfl_xor(sq,  off, 64);
  }
  const float mu = sum * (1.f / 1024.f);
  const float var = sq * (1.f / 1024.f) - mu * mu;
  const float inv = rsqrtf(var + 1e-5f);
  const int c0 = lane * 16;
  float* po = out + row * 1024 + lane * 16;
#pragma unroll
  for (int c = 0; c < 4; c++) {
    floatx4 o;
#pragma unroll
    for (int e = 0; e < 4; e++) {
      int j = c * 4 + e;
      o[e] = (f[j] - mu) * inv * gamma[c0 + j] + beta[c0 + j];
    }
    *(floatx4*)(po + c * 4) = o;
  }
}

extern "C" void kernel_launch(void* const* d_in, const int* in_sizes, int n_in,
                              void* d_out, int out_size, void* d_ws, size_t ws_size,
                              hipStream_t stream) {
  const float* x     = (const float*)d_in[0];
  const float* w_in  = (const float*)d_in[1];
  const float* b_in  = (const float*)d_in[2];
  const float* w_out = (const float*)d_in[3];
  const float* b_out = (const float*)d_in[4];
  const float* gamma = (const float*)d_in[5];
  const float* beta  = (const float*)d_in[6];
  const float* gate  = (const float*)d_in[7];
  float* out = (float*)d_out;   // f32 OUTPUT

  const int M = 32768;  // B*N = 4*8192
  char* ws = (char*)d_ws;
  uint16_t* w_in_bf  = (uint16_t*)ws;                   // 6 MiB
  uint16_t* w_out_bf = (uint16_t*)(ws + 6291456);       // 2 MiB
  uint16_t* x_bf     = (uint16_t*)(ws + 8388608);       // 64 MiB

  k_cvt_bf16<<<16384, 256, 0, stream>>>(x, x_bf, M * 1024 / 8);
  k_cvt_bf16<<<1536, 256, 0, stream>>>(w_in, w_in_bf, 393216);
  k_cvt_bf16<<<512, 256, 0, stream>>>(w_out, w_out_bf, 131072);

  const size_t full_need = 8388608ull + 67108864ull + 201326592ull + 67108864ull; // 344 MiB
  if (ws_size >= full_need) {
    // full-M path: qkv 192 MiB | attn 64 MiB; y_f32 reuses qkv (128 <= 192)
    uint16_t* qkv_bf  = (uint16_t*)(ws + 8388608 + 67108864);
    uint16_t* attn_bf = (uint16_t*)(ws + 8388608 + 67108864 + 201326592);
    float*    y_f32   = (float*)qkv_bf;
    const int nwg1 = (M / 128) * (3072 / 128);   // 6144, %8==0
    const int nwg2 = (M / 128) * (1024 / 128);   // 2048, %8==0
    k_gemm_qkv<<<nwg1, 256, 0, stream>>>(
        x_bf, w_in_bf, b_in, qkv_bf, 0, 1024, 3072, nwg1, 3072 / 128);
    k_attn<<<(M / 4) * 16 / 4, 256, 0, stream>>>(qkv_bf, attn_bf);
    k_gemm_out<<<nwg2, 256, 0, stream>>>(
        attn_bf, w_out_bf, b_out, x, gate, y_f32, 0, 1024, 1024, nwg2, 1024 / 128);
    k_ln<<<M / 4, 256, 0, stream>>>(y_f32, gamma, beta, out);
  } else {
    // chunked fallback
    uint16_t* qkv_bf  = (uint16_t*)(ws + 8388608 + 67108864);
    uint16_t* attn_bf = (uint16_t*)(ws + 8388608 + 67108864 + 50331648);
    float*    y_f32   = (float*)qkv_bf;
    const int CH = 8192;
    const int nwg1 = (CH / 128) * (3072 / 128);  // 1536, %8==0
    const int nwg2 = (CH / 128) * (1024 / 128);  // 512, %8==0
    for (int c = 0; c < 4; c++) {
      const int r0 = c * CH;
      k_gemm_qkv<<<nwg1, 256, 0, stream>>>(
          x_bf, w_in_bf, b_in, qkv_bf, r0, 1024, 3072, nwg1, 3072 / 128);
      k_attn<<<(CH / 4) * 16 / 4, 256, 0, stream>>>(qkv_bf, attn_bf);
      k_gemm_out<<<nwg2, 256, 0, stream>>>(
          attn_bf, w_out_bf, b_out, x, gate, y_f32, r0, 1024, 1024, nwg2, 1024 / 128);
      k_ln<<<CH / 4, 256, 0, stream>>>(y_f32, gamma, beta, out + (size_t)r0 * 1024);
    }
  }
}